// Round 1
// baseline (321.970 us; speedup 1.0000x reference)
//
#include <hip/hip_runtime.h>
#include <math.h>

#define Bq 4
#define Hq 512
#define Nq 64
#define Lq 2048
#define PARAM (Hq*Nq)   // 32768

// ---------------------------------------------------------------------------
// Phase 1: per-(h,n) parameter prep.
//   w  = exp(dt*A)                (complex, A = -exp(log_A_real) + i*A_imag)
//   dB = B * (w-1)/A
//   CB = C * dB ;  store a = 2*Re(CB), b = -2*Im(CB) so y += a*sr + b*si
// ---------------------------------------------------------------------------
__global__ void prep_kernel(const float* __restrict__ log_dt,
                            const float* __restrict__ log_A_real,
                            const float* __restrict__ A_imag,
                            const float* __restrict__ B_re, const float* __restrict__ B_im,
                            const float* __restrict__ C_re, const float* __restrict__ C_im,
                            float* __restrict__ wr_, float* __restrict__ wi_,
                            float* __restrict__ a0, float* __restrict__ b0,
                            float* __restrict__ a1, float* __restrict__ b1) {
    int idx = blockIdx.x * blockDim.x + threadIdx.x;
    if (idx >= PARAM) return;
    int h = idx >> 6;            // idx / Nq
    float dt = expf(log_dt[h]);
    float Ar = -expf(log_A_real[idx]);
    float Ai = A_imag[idx];
    float er = expf(Ar * dt);
    float wr = er * cosf(Ai * dt);
    float wi = er * sinf(Ai * dt);
    wr_[idx] = wr; wi_[idx] = wi;
    // (w-1)/A
    float mr = wr - 1.0f, mi = wi;
    float den = Ar * Ar + Ai * Ai;
    float qr = (mr * Ar + mi * Ai) / den;
    float qi = (mi * Ar - mr * Ai) / den;
    float Br = B_re[idx], Bi = B_im[idx];
    float dBr = Br * qr - Bi * qi;
    float dBi = Br * qi + Bi * qr;
    // dir 0
    float cr = C_re[idx], ci = C_im[idx];
    a0[idx] =  2.0f * (cr * dBr - ci * dBi);
    b0[idx] = -2.0f * (cr * dBi + ci * dBr);
    // dir 1
    cr = C_re[PARAM + idx]; ci = C_im[PARAM + idx];
    a1[idx] =  2.0f * (cr * dBr - ci * dBi);
    b1[idx] = -2.0f * (cr * dBi + ci * dBr);
}

// ---------------------------------------------------------------------------
// Phase 2: LayerNorm over channel dim H for each (b,l).
// block = 256 threads = 16 l-lanes x 16 h-groups; grid = B * (L/16)
// ---------------------------------------------------------------------------
__global__ __launch_bounds__(256)
void ln_kernel(const float* __restrict__ x, const float* __restrict__ lnw,
               const float* __restrict__ lnb, float* __restrict__ z) {
    int blk = blockIdx.x;
    int b  = blk / (Lq / 16);
    int l0 = (blk % (Lq / 16)) * 16;
    int tx = threadIdx.x & 15;   // l within tile
    int ty = threadIdx.x >> 4;   // h group
    const float* xb = x + (size_t)b * Hq * Lq;
    float s = 0.f, s2 = 0.f;
    for (int h = ty; h < Hq; h += 16) {
        float v = xb[h * Lq + l0 + tx];
        s += v; s2 += v * v;
    }
    __shared__ float rs_[16][17], r2_[16][17], mu_s[16], sg_s[16];
    rs_[ty][tx] = s; r2_[ty][tx] = s2;
    __syncthreads();
    if (ty == 0) {
        float a = 0.f, c = 0.f;
        #pragma unroll
        for (int i = 0; i < 16; ++i) { a += rs_[i][tx]; c += r2_[i][tx]; }
        float mu = a * (1.0f / Hq);
        float var = c * (1.0f / Hq) - mu * mu;
        mu_s[tx] = mu;
        sg_s[tx] = rsqrtf(var + 1e-5f);
    }
    __syncthreads();
    float mu = mu_s[tx], rs = sg_s[tx];
    float* zb = z + (size_t)b * Hq * Lq;
    for (int h = ty; h < Hq; h += 16) {
        float v = xb[h * Lq + l0 + tx];
        zb[h * Lq + l0 + tx] = (v - mu) * rs * lnw[h] + lnb[h];
    }
}

// ---------------------------------------------------------------------------
// Phase 3: SSM scans. One wave per (b,h,dir); lane n = state index.
// DIR 0: s_t = w*s + z[t]  (update THEN output)   y0[t] = a*sr + b*si
// DIR 1: output THEN r = w*r + z[t]  iterating t = L-1 .. 0
// 32 timesteps buffered in registers, reduced across the 64 lanes via a
// padded LDS transpose (2-way bank aliasing only -> free).
// ---------------------------------------------------------------------------
template <int DIR>
__device__ __forceinline__ void scan_body(const float* __restrict__ zz,
                                          float* __restrict__ yout,
                                          float wr, float wi, float a, float b,
                                          float (*tile)[33], float* zbuf, int n) {
    float sr = 0.f, si = 0.f;
    for (int q0 = 0; q0 < Lq; q0 += 32) {
        if (n < 32) zbuf[n] = zz[DIR ? (Lq - 1 - q0 - n) : (q0 + n)];
        __syncthreads();
        float p[32];
        #pragma unroll
        for (int k = 0; k < 32; ++k) {
            float zt = zbuf[k];
            if (DIR == 0) {
                float t1 = fmaf(wi, si, -zt);   // wi*si - z
                float t2 = wi * sr;
                sr = fmaf(wr, sr, -t1);         // wr*sr - wi*si + z
                si = fmaf(wr, si, t2);
                p[k] = fmaf(a, sr, b * si);
            } else {
                p[k] = fmaf(a, sr, b * si);
                float t1 = fmaf(wi, si, -zt);
                float t2 = wi * sr;
                sr = fmaf(wr, sr, -t1);
                si = fmaf(wr, si, t2);
            }
        }
        #pragma unroll
        for (int k = 0; k < 32; ++k) tile[n][k] = p[k];
        __syncthreads();
        int tloc = n & 31, ih = n >> 5;
        float acc = 0.f;
        #pragma unroll
        for (int j = 0; j < 32; ++j) acc += tile[ih * 32 + j][tloc];
        acc += __shfl_xor(acc, 32, 64);
        if (n < 32) yout[DIR ? (Lq - 1 - q0 - n) : (q0 + n)] = acc;
        // next round's zbuf write is separated from this round's zbuf reads by
        // the post-tile barrier; tile rewrite is separated by next pre-compute
        // barrier. (single-wave block: barriers are ~free)
    }
}

__global__ __launch_bounds__(64)
void scan_kernel(const float* __restrict__ z,
                 const float* __restrict__ wr_, const float* __restrict__ wi_,
                 const float* __restrict__ a0, const float* __restrict__ b0,
                 const float* __restrict__ a1, const float* __restrict__ b1,
                 float* __restrict__ y0, float* __restrict__ y1) {
    int bh  = blockIdx.x;            // b*H + h
    int dir = blockIdx.y;
    int h = bh & (Hq - 1);
    int n = threadIdx.x;
    int pidx = h * Nq + n;
    float wr = wr_[pidx], wi = wi_[pidx];
    __shared__ float tile[64][33];
    __shared__ float zbuf[32];
    const float* zz = z + (size_t)bh * Lq;
    if (dir == 0) {
        scan_body<0>(zz, y0 + (size_t)bh * Lq, wr, wi, a0[pidx], b0[pidx], tile, zbuf, n);
    } else {
        scan_body<1>(zz, y1 + (size_t)bh * Lq, wr, wi, a1[pidx], b1[pidx], tile, zbuf, n);
    }
}

// ---------------------------------------------------------------------------
// Phase 4: u = gelu_tanh(y0 + y1 + D*z), written in-place into y0.
// ---------------------------------------------------------------------------
__global__ __launch_bounds__(256)
void act_kernel(float4* __restrict__ y0, const float4* __restrict__ y1,
                const float4* __restrict__ z, const float* __restrict__ D) {
    int i4 = blockIdx.x * 256 + threadIdx.x;       // B*H*L/4 = 1048576
    int h = (i4 >> 9) & (Hq - 1);                  // (i4*4 / L) % H
    float d = D[h];
    float4 v0 = y0[i4], v1 = y1[i4], vz = z[i4];
    float vv[4] = { v0.x + v1.x + d * vz.x, v0.y + v1.y + d * vz.y,
                    v0.z + v1.z + d * vz.z, v0.w + v1.w + d * vz.w };
    #pragma unroll
    for (int i = 0; i < 4; ++i) {
        float v = vv[i];
        float t = tanhf(0.7978845608028654f * (v + 0.044715f * v * v * v));
        vv[i] = 0.5f * v * (1.0f + t);
    }
    float4 r; r.x = vv[0]; r.y = vv[1]; r.z = vv[2]; r.w = vv[3];
    y0[i4] = r;
}

// ---------------------------------------------------------------------------
// Phase 5: out[b,o,l] = bias[o] + x[b,o,l] + sum_h W[o,h]*u[b,h,l]
// fp32 tiled GEMM: block tile 128(o) x 64(l), 256 threads, 8x4 microtile.
// ---------------------------------------------------------------------------
__global__ __launch_bounds__(256)
void gemm_kernel(const float* __restrict__ u, const float* __restrict__ W,
                 const float* __restrict__ bias, const float* __restrict__ x,
                 float* __restrict__ out) {
    int l0 = blockIdx.x * 64;
    int o0 = blockIdx.y * 128;
    int b  = blockIdx.z;
    int tid = threadIdx.x;
    __shared__ float Ws[16][129];   // [k][o]
    __shared__ float Us[16][65];    // [k][l]
    const float* ub = u + (size_t)b * Hq * Lq;
    float acc[8][4] = {};
    int wo = tid >> 4, wl = tid & 15;
    for (int k0 = 0; k0 < Hq; k0 += 16) {
        {
            int j  = tid & 15;       // k
            int ib = tid >> 4;       // o base
            #pragma unroll
            for (int r = 0; r < 8; ++r) {
                int i = ib + 16 * r;
                Ws[j][i] = W[(size_t)(o0 + i) * Hq + k0 + j];
            }
            int li = tid & 63;
            int jb = tid >> 6;
            #pragma unroll
            for (int r = 0; r < 4; ++r) {
                int j2 = jb + 4 * r;
                Us[j2][li] = ub[(size_t)(k0 + j2) * Lq + l0 + li];
            }
        }
        __syncthreads();
        #pragma unroll
        for (int j = 0; j < 16; ++j) {
            float av[8], bv[4];
            #pragma unroll
            for (int i = 0; i < 8; ++i) av[i] = Ws[j][8 * wo + i];
            #pragma unroll
            for (int i = 0; i < 4; ++i) bv[i] = Us[j][4 * wl + i];
            #pragma unroll
            for (int io = 0; io < 8; ++io)
                #pragma unroll
                for (int il = 0; il < 4; ++il)
                    acc[io][il] = fmaf(av[io], bv[il], acc[io][il]);
        }
        __syncthreads();
    }
    #pragma unroll
    for (int io = 0; io < 8; ++io) {
        int o = o0 + 8 * wo + io;
        float bo = bias[o];
        size_t base = ((size_t)b * Hq + o) * Lq + l0 + 4 * wl;
        const float4 xr = *(const float4*)(x + base);
        float4 r;
        r.x = acc[io][0] + bo + xr.x;
        r.y = acc[io][1] + bo + xr.y;
        r.z = acc[io][2] + bo + xr.z;
        r.w = acc[io][3] + bo + xr.w;
        *(float4*)(out + base) = r;
    }
}

// ---------------------------------------------------------------------------
extern "C" void kernel_launch(void* const* d_in, const int* in_sizes, int n_in,
                              void* d_out, int out_size, void* d_ws, size_t ws_size,
                              hipStream_t stream) {
    (void)in_sizes; (void)n_in; (void)out_size; (void)ws_size;
    const float* x          = (const float*)d_in[0];
    const float* ln_w       = (const float*)d_in[1];
    const float* ln_b       = (const float*)d_in[2];
    const float* log_dt     = (const float*)d_in[3];
    const float* log_A_real = (const float*)d_in[4];
    const float* A_imag     = (const float*)d_in[5];
    const float* B_re       = (const float*)d_in[6];
    const float* B_im       = (const float*)d_in[7];
    const float* C_re       = (const float*)d_in[8];
    const float* C_im       = (const float*)d_in[9];
    const float* Dv         = (const float*)d_in[10];
    const float* W          = (const float*)d_in[11];
    const float* b_out      = (const float*)d_in[12];
    float* out = (float*)d_out;
    float* ws  = (float*)d_ws;

    float* wr = ws;
    float* wi = ws + PARAM;
    float* a0 = ws + 2 * PARAM;
    float* b0 = ws + 3 * PARAM;
    float* a1 = ws + 4 * PARAM;
    float* b1 = ws + 5 * PARAM;
    float* z  = ws + 6 * PARAM;                    // B*H*L
    float* y0 = z  + (size_t)Bq * Hq * Lq;         // also holds u after act
    float* y1 = y0 + (size_t)Bq * Hq * Lq;

    prep_kernel<<<PARAM / 256, 256, 0, stream>>>(log_dt, log_A_real, A_imag,
                                                 B_re, B_im, C_re, C_im,
                                                 wr, wi, a0, b0, a1, b1);
    ln_kernel<<<Bq * (Lq / 16), 256, 0, stream>>>(x, ln_w, ln_b, z);
    scan_kernel<<<dim3(Bq * Hq, 2), 64, 0, stream>>>(z, wr, wi, a0, b0, a1, b1, y0, y1);
    act_kernel<<<(Bq * Hq * Lq / 4) / 256, 256, 0, stream>>>((float4*)y0, (const float4*)y1,
                                                             (const float4*)z, Dv);
    gemm_kernel<<<dim3(Lq / 64, Hq / 128, Bq), 256, 0, stream>>>(y0, W, b_out, x, out);
}